// Round 1
// baseline (8293.649 us; speedup 1.0000x reference)
//
#include <hip/hip_runtime.h>
#include <hip/hip_bf16.h>

// Problem dims
#define BB 64
#define TT 512
#define DD 256
#define HH 512
#define GG 2048            // 4*HH
#define SS (BB*HH)         // 32768 elems per [B,H] slab
#define NBLK 192           // 3 layers x 64 column-slices
#define NTHR 256
#define KPAD 1032          // 1024 + 8 bf16 pad (breaks pow2 LDS stride)

using short8 = __attribute__((ext_vector_type(8))) short;
using f32x4  = __attribute__((ext_vector_type(4))) float;
using f4     = __attribute__((ext_vector_type(4))) float;

// Grid-barrier state. Zero-initialized at module load; counter always returns
// to 0 after a completed barrier, generation is used relative to a per-call
// snapshot -> safe across graph replays, no workspace init dependency.
__device__ unsigned g_counter = 0;
__device__ unsigned g_gen = 0;

__device__ __forceinline__ short f2bf(float f) {
  unsigned u = __builtin_bit_cast(unsigned, f);
  u = (u + 0x7fffu + ((u >> 16) & 1u)) >> 16;   // RNE
  return (short)u;
}
__device__ __forceinline__ float sigm(float x)  { return 1.f / (1.f + __expf(-x)); }
__device__ __forceinline__ float tanh_(float x) { return 2.f / (1.f + __expf(-2.f * x)) - 1.f; }

__device__ __forceinline__ void grid_barrier(unsigned target) {
  __syncthreads();
  if (threadIdx.x == 0) {
    __builtin_amdgcn_fence(__ATOMIC_RELEASE, "agent");   // flush XCD L2 (writeback)
    unsigned old = __hip_atomic_fetch_add(&g_counter, 1u, __ATOMIC_RELAXED,
                                          __HIP_MEMORY_SCOPE_AGENT);
    if (old == NBLK - 1) {
      __hip_atomic_store(&g_counter, 0u, __ATOMIC_RELAXED, __HIP_MEMORY_SCOPE_AGENT);
      __hip_atomic_store(&g_gen, target, __ATOMIC_RELEASE, __HIP_MEMORY_SCOPE_AGENT);
    } else {
      while ((int)(__hip_atomic_load(&g_gen, __ATOMIC_RELAXED,
                                     __HIP_MEMORY_SCOPE_AGENT) - target) < 0)
        __builtin_amdgcn_s_sleep(1);
    }
    __builtin_amdgcn_fence(__ATOMIC_ACQUIRE, "agent");   // invalidate L1/L2 for fresh h reads
  }
  __syncthreads();
}

extern "C" __global__ __launch_bounds__(NTHR, 1) void lstm_persistent(
    const float* __restrict__ x,
    const float* __restrict__ W0, const float* __restrict__ U0, const float* __restrict__ b0,
    const float* __restrict__ W1, const float* __restrict__ U1, const float* __restrict__ b1,
    const float* __restrict__ W2, const float* __restrict__ U2, const float* __restrict__ b2,
    float* __restrict__ out,
    unsigned short* __restrict__ hbuf)   // [3 layers][2 parity][B][H] bf16 ring in d_ws
{
  __shared__ unsigned short Wl[32][KPAD];   // weight slice, bf16: 66048 B
  __shared__ float Zp[4][BB][33];           // per-wave partial Z: 33792 B
  __shared__ float cl[BB * 8];              // cell state (f32), thread-owned: 2048 B
  __shared__ float biasl[32];
  __shared__ unsigned s_gen0;

  const int tid = threadIdx.x;
  const int bid = blockIdx.x;
  const int l = bid % 3;            // layer
  const int slice = bid / 3;        // 0..63
  const int j0 = slice * 8;         // first h-column owned

  if (tid == 0)
    s_gen0 = __hip_atomic_load(&g_gen, __ATOMIC_ACQUIRE, __HIP_MEMORY_SCOPE_AGENT);

  const float* Wsrc = (l == 0) ? W0 : (l == 1) ? W1 : W2;
  const float* Usrc = (l == 0) ? U0 : (l == 1) ? U1 : U2;
  const float* bsrc = (l == 0) ? b0 : (l == 1) ? b1 : b2;
  const int Kx = (l == 0) ? DD : HH;        // x-part K
  const int Ktot = Kx + HH;                 // 768 or 1024

  // ---- prologue: stage weight slice (f32 -> bf16) into LDS, row n = gate col ----
  for (int q = 0; q < 4; ++q) {             // gate order i,f,g,o
    const int gcol = q * HH + j0;
    for (int k = tid; k < Kx; k += NTHR) {
      const float* s = Wsrc + (size_t)k * GG + gcol;
      #pragma unroll
      for (int c = 0; c < 8; ++c) Wl[q * 8 + c][k] = (unsigned short)f2bf(s[c]);
    }
    for (int k = tid; k < HH; k += NTHR) {
      const float* s = Usrc + (size_t)k * GG + gcol;
      #pragma unroll
      for (int c = 0; c < 8; ++c) Wl[q * 8 + c][Kx + k] = (unsigned short)f2bf(s[c]);
    }
  }
  if (tid < 32) biasl[tid] = bsrc[(tid >> 3) * HH + j0 + (tid & 7)];
  for (int i = tid; i < BB * 8; i += NTHR) cl[i] = 0.f;

  // zero the h ring (ws is poisoned 0xAA before every call)
  {
    unsigned* hz = (unsigned*)hbuf;
    const int n = 3 * 2 * SS / 2;           // 98304 uints
    for (int i = bid * NTHR + tid; i < n; i += NBLK * NTHR) hz[i] = 0u;
  }

  __syncthreads();
  unsigned bt = s_gen0;
  bt += 1; grid_barrier(bt);

  const int lane = tid & 63;
  const int wv = tid >> 6;                  // wave 0..3: K-quarter
  const int m = lane & 15;                  // A-operand row (batch within tile)
  const int quad = lane >> 4;
  const int col = lane & 15;                // B-operand col / C col
  const int nchunks = Ktot / 128;           // K32-chunks per wave: 6 or 8
  const int ck0 = wv * nchunks;

  for (int r = 0; r < TT + 2; ++r) {
    const int t = r - l;                    // pipelined wavefront
    if (0 <= t && t < TT) {
      const int rp = (r + 1) & 1;           // read parity  = (r-1)&1
      const int wp = r & 1;                 // write parity
      const unsigned short* h_self  = hbuf + (l * 2 + rp) * SS;
      const unsigned short* h_below = (l > 0) ? hbuf + ((l - 1) * 2 + rp) * SS
                                              : (const unsigned short*)0;

      f32x4 acc[4][2];
      #pragma unroll
      for (int mt = 0; mt < 4; ++mt) {
        acc[mt][0] = (f32x4){0.f, 0.f, 0.f, 0.f};
        acc[mt][1] = (f32x4){0.f, 0.f, 0.f, 0.f};
      }

      for (int c = 0; c < nchunks; ++c) {
        const int kk = (ck0 + c) * 32 + quad * 8;   // chunk-uniform piece select
        short8 a[4];
        if (l == 0) {
          if (kk < DD) {                    // x piece: f32 load + convert
            #pragma unroll
            for (int mt = 0; mt < 4; ++mt) {
              const float* p = x + ((size_t)(16 * mt + m) * TT + t) * DD + kk;
              f4 v0 = *(const f4*)p;
              f4 v1 = *(const f4*)(p + 4);
              a[mt] = (short8){f2bf(v0[0]), f2bf(v0[1]), f2bf(v0[2]), f2bf(v0[3]),
                               f2bf(v1[0]), f2bf(v1[1]), f2bf(v1[2]), f2bf(v1[3])};
            }
          } else {                          // h_self piece (bf16)
            const int ko = kk - DD;
            #pragma unroll
            for (int mt = 0; mt < 4; ++mt)
              a[mt] = *(const short8*)(h_self + (16 * mt + m) * HH + ko);
          }
        } else {
          const unsigned short* hs = (kk < HH) ? h_below : h_self;
          const int ko = (kk < HH) ? kk : kk - HH;
          #pragma unroll
          for (int mt = 0; mt < 4; ++mt)
            a[mt] = *(const short8*)(hs + (16 * mt + m) * HH + ko);
        }
        short8 bfr0 = *(const short8*)&Wl[col][kk];
        short8 bfr1 = *(const short8*)&Wl[16 + col][kk];
        #pragma unroll
        for (int mt = 0; mt < 4; ++mt) {
          acc[mt][0] = __builtin_amdgcn_mfma_f32_16x16x32_bf16(a[mt], bfr0, acc[mt][0], 0, 0, 0);
          acc[mt][1] = __builtin_amdgcn_mfma_f32_16x16x32_bf16(a[mt], bfr1, acc[mt][1], 0, 0, 0);
        }
      }

      // C/D layout: col = lane&15, row = quad*4 + reg  -> partial Z to LDS
      #pragma unroll
      for (int mt = 0; mt < 4; ++mt) {
        #pragma unroll
        for (int rg = 0; rg < 4; ++rg) {
          Zp[wv][16 * mt + quad * 4 + rg][col]      = acc[mt][0][rg];
          Zp[wv][16 * mt + quad * 4 + rg][16 + col] = acc[mt][1][rg];
        }
      }
      __syncthreads();

      // ---- phase 2: gates + state update (each thread owns 2 (b,j) items) ----
      unsigned short* h_out = hbuf + (l * 2 + wp) * SS;
      #pragma unroll
      for (int s2 = 0; s2 < 2; ++s2) {
        const int item = tid + NTHR * s2;
        const int b_ = item >> 3;
        const int j  = item & 7;
        float zi = biasl[j], zf = biasl[8 + j], zg = biasl[16 + j], zo = biasl[24 + j];
        #pragma unroll
        for (int w2 = 0; w2 < 4; ++w2) {
          zi += Zp[w2][b_][j];
          zf += Zp[w2][b_][8 + j];
          zg += Zp[w2][b_][16 + j];
          zo += Zp[w2][b_][24 + j];
        }
        const float gi = sigm(zi), gf = sigm(zf), gz = tanh_(zg), go = sigm(zo);
        const float cc = gf * cl[item] + gi * gz;
        cl[item] = cc;
        const float hh = go * tanh_(cc);
        h_out[b_ * HH + j0 + j] = (unsigned short)f2bf(hh);
        if (t == TT - 1) {
          const int oidx = b_ * HH + j0 + j;
          if (l == 0)      { out[SS + oidx] = hh;     out[2 * SS + oidx] = cc; }
          else if (l == 1) { out[3 * SS + oidx] = hh; out[4 * SS + oidx] = cc; }
          else             { out[oidx] = hh; out[5 * SS + oidx] = hh; out[6 * SS + oidx] = cc; }
        }
      }
    }
    bt += 1; grid_barrier(bt);
  }
}

extern "C" void kernel_launch(void* const* d_in, const int* in_sizes, int n_in,
                              void* d_out, int out_size, void* d_ws, size_t ws_size,
                              hipStream_t stream) {
  const float* x  = (const float*)d_in[0];
  const float* W0 = (const float*)d_in[1];
  const float* U0 = (const float*)d_in[2];
  const float* b0 = (const float*)d_in[3];
  const float* W1 = (const float*)d_in[4];
  const float* U1 = (const float*)d_in[5];
  const float* b1 = (const float*)d_in[6];
  const float* W2 = (const float*)d_in[7];
  const float* U2 = (const float*)d_in[8];
  const float* b2 = (const float*)d_in[9];
  float* out = (float*)d_out;
  unsigned short* hbuf = (unsigned short*)d_ws;   // 393216 B used

  void* args[] = {(void*)&x,
                  (void*)&W0, (void*)&U0, (void*)&b0,
                  (void*)&W1, (void*)&U1, (void*)&b1,
                  (void*)&W2, (void*)&U2, (void*)&b2,
                  (void*)&out, (void*)&hbuf};
  hipLaunchCooperativeKernel((void*)lstm_persistent, dim3(NBLK), dim3(NTHR),
                             args, 0, stream);
}

// Round 2
// 5079.099 us; speedup vs baseline: 1.6329x; 1.6329x over previous
//
#include <hip/hip_runtime.h>
#include <hip/hip_bf16.h>

// Problem dims
#define BB 64
#define TT 512
#define DD 256
#define HH 512
#define GG 2048            // 4*HH
#define SS (BB*HH)         // 32768 elems per [B,H] slab
#define NBLK 192           // 3 layers x 64 column-slices
#define NTHR 256
#define KPAD 1032          // 1024 + 8 bf16 pad

using short8 = __attribute__((ext_vector_type(8))) short;
using f32x4  = __attribute__((ext_vector_type(4))) float;
using f4     = __attribute__((ext_vector_type(4))) float;

// Single-word barrier: low 32 = arrival counter, high 32 = generation.
// Publish+reset in ONE atomic RMW -> no reset/arrival race. Zero-init at load;
// generation only consumed relative to a per-call snapshot -> graph-replay safe.
__device__ unsigned long long g_word = 0;

__device__ __forceinline__ short f2bf(float f) {
  unsigned u = __builtin_bit_cast(unsigned, f);
  u = (u + 0x7fffu + ((u >> 16) & 1u)) >> 16;   // RNE
  return (short)u;
}
__device__ __forceinline__ float sigm(float x)  { return 1.f / (1.f + __expf(-x)); }
__device__ __forceinline__ float tanh_(float x) { return 2.f / (1.f + __expf(-2.f * x)) - 1.f; }

// ---- IC-coherent (sc0 sc1) async loads/stores, explicit vmcnt pipeline ----
__device__ __forceinline__ void issueH(short8& a0, short8& a1, short8& a2, short8& a3,
                                       const unsigned short* p0, const unsigned short* p1,
                                       const unsigned short* p2, const unsigned short* p3) {
  asm volatile("global_load_dwordx4 %0, %4, off sc0 sc1\n\t"
               "global_load_dwordx4 %1, %5, off sc0 sc1\n\t"
               "global_load_dwordx4 %2, %6, off sc0 sc1\n\t"
               "global_load_dwordx4 %3, %7, off sc0 sc1"
               : "=&v"(a0), "=&v"(a1), "=&v"(a2), "=&v"(a3)
               : "v"(p0), "v"(p1), "v"(p2), "v"(p3));
}
// x is immutable -> normally cached loads (still vmcnt-counted)
__device__ __forceinline__ void issueX(f4& x0, f4& x1, f4& x2, f4& x3,
                                       f4& x4, f4& x5, f4& x6, f4& x7,
                                       const float* p0, const float* p1,
                                       const float* p2, const float* p3) {
  asm volatile("global_load_dwordx4 %0, %8, off\n\t"
               "global_load_dwordx4 %1, %8, off offset:16\n\t"
               "global_load_dwordx4 %2, %9, off\n\t"
               "global_load_dwordx4 %3, %9, off offset:16\n\t"
               "global_load_dwordx4 %4, %10, off\n\t"
               "global_load_dwordx4 %5, %10, off offset:16\n\t"
               "global_load_dwordx4 %6, %11, off\n\t"
               "global_load_dwordx4 %7, %11, off offset:16"
               : "=&v"(x0), "=&v"(x1), "=&v"(x2), "=&v"(x3),
                 "=&v"(x4), "=&v"(x5), "=&v"(x6), "=&v"(x7)
               : "v"(p0), "v"(p1), "v"(p2), "v"(p3));
}
__device__ __forceinline__ void waitA4(short8& a0, short8& a1, short8& a2, short8& a3) {
  asm volatile("s_waitcnt vmcnt(4)" : "+v"(a0), "+v"(a1), "+v"(a2), "+v"(a3));
}
__device__ __forceinline__ void waitA8(short8& a0, short8& a1, short8& a2, short8& a3) {
  asm volatile("s_waitcnt vmcnt(8)" : "+v"(a0), "+v"(a1), "+v"(a2), "+v"(a3));
}
__device__ __forceinline__ void waitA0(short8& a0, short8& a1, short8& a2, short8& a3) {
  asm volatile("s_waitcnt vmcnt(0)" : "+v"(a0), "+v"(a1), "+v"(a2), "+v"(a3));
}
__device__ __forceinline__ void waitX8(f4& x0, f4& x1, f4& x2, f4& x3,
                                       f4& x4, f4& x5, f4& x6, f4& x7) {
  asm volatile("s_waitcnt vmcnt(8)"
               : "+v"(x0), "+v"(x1), "+v"(x2), "+v"(x3),
                 "+v"(x4), "+v"(x5), "+v"(x6), "+v"(x7));
}
__device__ __forceinline__ void waitX0(f4& x0, f4& x1, f4& x2, f4& x3,
                                       f4& x4, f4& x5, f4& x6, f4& x7) {
  asm volatile("s_waitcnt vmcnt(0)"
               : "+v"(x0), "+v"(x1), "+v"(x2), "+v"(x3),
                 "+v"(x4), "+v"(x5), "+v"(x6), "+v"(x7));
}
__device__ __forceinline__ void stH(unsigned short* p, unsigned v) {
  asm volatile("global_store_dword %0, %1, off sc0 sc1" :: "v"(p), "v"(v) : "memory");
}

__device__ __forceinline__ short8 pack8(const f4& lo, const f4& hi) {
  return (short8){f2bf(lo[0]), f2bf(lo[1]), f2bf(lo[2]), f2bf(lo[3]),
                  f2bf(hi[0]), f2bf(hi[1]), f2bf(hi[2]), f2bf(hi[3])};
}

// Fence-free grid barrier: h traffic is sc1 (IC-coherent), so no cache
// maintenance is needed -- just drain vmem, then one atomic RMW.
__device__ __forceinline__ void grid_barrier(unsigned target) {
  asm volatile("s_waitcnt vmcnt(0)" ::: "memory");
  __syncthreads();
  if (threadIdx.x == 0) {
    unsigned long long old = __hip_atomic_fetch_add(&g_word, 1ull, __ATOMIC_RELAXED,
                                                    __HIP_MEMORY_SCOPE_AGENT);
    if ((unsigned)(old & 0xffffffffull) == NBLK - 1) {
      __hip_atomic_fetch_add(&g_word, (1ull << 32) - (unsigned long long)NBLK,
                             __ATOMIC_RELAXED, __HIP_MEMORY_SCOPE_AGENT);
    } else {
      while ((int)((unsigned)(__hip_atomic_load(&g_word, __ATOMIC_RELAXED,
                                                __HIP_MEMORY_SCOPE_AGENT) >> 32) - target) < 0)
        __builtin_amdgcn_s_sleep(2);
    }
  }
  __syncthreads();
}

extern "C" __global__ __launch_bounds__(NTHR, 1) void lstm_persistent(
    const float* __restrict__ x,
    const float* __restrict__ W0, const float* __restrict__ U0, const float* __restrict__ b0,
    const float* __restrict__ W1, const float* __restrict__ U1, const float* __restrict__ b1,
    const float* __restrict__ W2, const float* __restrict__ U2, const float* __restrict__ b2,
    float* __restrict__ out,
    unsigned short* __restrict__ hbuf)   // [3][2 parity][B][H] bf16 ring in d_ws
{
  __shared__ unsigned short Wl[32][KPAD];   // 66048 B
  __shared__ float Zp[4][BB][34];           // 34816 B (pad 34: 2-way-free writes, b64-aligned reads)
  __shared__ float cl[BB * 8];              // 2048 B
  __shared__ float biasl[32];
  __shared__ unsigned s_gen0;

  const int tid = threadIdx.x;
  const int bid = blockIdx.x;
  const int l = bid % 3;
  const int slice = bid / 3;
  const int j0 = slice * 8;

  if (tid == 0)
    s_gen0 = (unsigned)(__hip_atomic_load(&g_word, __ATOMIC_RELAXED,
                                          __HIP_MEMORY_SCOPE_AGENT) >> 32);

  const float* Wsrc = (l == 0) ? W0 : (l == 1) ? W1 : W2;
  const float* Usrc = (l == 0) ? U0 : (l == 1) ? U1 : U2;
  const float* bsrc = (l == 0) ? b0 : (l == 1) ? b1 : b2;
  const int Kx = (l == 0) ? DD : HH;

  // ---- prologue: stage weight slice (f32 -> bf16) into LDS ----
  for (int q = 0; q < 4; ++q) {
    const int gcol = q * HH + j0;
    for (int k = tid; k < Kx; k += NTHR) {
      const float* s = Wsrc + (size_t)k * GG + gcol;
      #pragma unroll
      for (int c = 0; c < 8; ++c) Wl[q * 8 + c][k] = (unsigned short)f2bf(s[c]);
    }
    for (int k = tid; k < HH; k += NTHR) {
      const float* s = Usrc + (size_t)k * GG + gcol;
      #pragma unroll
      for (int c = 0; c < 8; ++c) Wl[q * 8 + c][Kx + k] = (unsigned short)f2bf(s[c]);
    }
  }
  if (tid < 32) biasl[tid] = bsrc[(tid >> 3) * HH + j0 + (tid & 7)];
  for (int i = tid; i < BB * 8; i += NTHR) cl[i] = 0.f;

  // zero h ring with sc1 stores (IC-visible cross-XCD without fences)
  {
    const int n = 3 * 2 * SS / 2;           // dwords
    for (int i = bid * NTHR + tid; i < n; i += NBLK * NTHR)
      stH((unsigned short*)hbuf + 2 * i, 0u);
  }

  __syncthreads();
  unsigned bt = s_gen0;
  bt += 1; grid_barrier(bt);

  const int lane = tid & 63;
  const int wv = tid >> 6;
  const int m = lane & 15;
  const int quad = lane >> 4;
  const int col = lane & 15;

  for (int r = 0; r < TT + 2; ++r) {
    const int t = r - l;
    if (0 <= t && t < TT) {
      const int rp = (r + 1) & 1;
      const int wp = r & 1;
      const unsigned short* h_self  = hbuf + (l * 2 + rp) * SS;
      const unsigned short* h_below = (l > 0) ? hbuf + ((l - 1) * 2 + rp) * SS
                                              : (const unsigned short*)0;

      f32x4 acc[4][2];
      #pragma unroll
      for (int mt = 0; mt < 4; ++mt) {
        acc[mt][0] = (f32x4){0.f, 0.f, 0.f, 0.f};
        acc[mt][1] = (f32x4){0.f, 0.f, 0.f, 0.f};
      }

      #define MFMA_CHUNK(AV, KKG)                                                     \
        do {                                                                          \
          short8 bf0 = *(const short8*)&Wl[col][(KKG)];                               \
          short8 bf1 = *(const short8*)&Wl[16 + col][(KKG)];                          \
          acc[0][0] = __builtin_amdgcn_mfma_f32_16x16x32_bf16((AV)[0], bf0, acc[0][0], 0, 0, 0); \
          acc[0][1] = __builtin_amdgcn_mfma_f32_16x16x32_bf16((AV)[0], bf1, acc[0][1], 0, 0, 0); \
          acc[1][0] = __builtin_amdgcn_mfma_f32_16x16x32_bf16((AV)[1], bf0, acc[1][0], 0, 0, 0); \
          acc[1][1] = __builtin_amdgcn_mfma_f32_16x16x32_bf16((AV)[1], bf1, acc[1][1], 0, 0, 0); \
          acc[2][0] = __builtin_amdgcn_mfma_f32_16x16x32_bf16((AV)[2], bf0, acc[2][0], 0, 0, 0); \
          acc[2][1] = __builtin_amdgcn_mfma_f32_16x16x32_bf16((AV)[2], bf1, acc[2][1], 0, 0, 0); \
          acc[3][0] = __builtin_amdgcn_mfma_f32_16x16x32_bf16((AV)[3], bf0, acc[3][0], 0, 0, 0); \
          acc[3][1] = __builtin_amdgcn_mfma_f32_16x16x32_bf16((AV)[3], bf1, acc[3][1], 0, 0, 0); \
        } while (0)

      if (l > 0) {
        // K=1024 split: waves 0,1 -> h_below k in [0,512); waves 2,3 -> h_self
        const unsigned short* src = (wv < 2) ? h_below : h_self;
        const int ko0 = (wv & 1) * 256 + quad * 8;
        const unsigned short* pA[4];
        #pragma unroll
        for (int mt = 0; mt < 4; ++mt) pA[mt] = src + (16 * mt + m) * HH + ko0;

        short8 u0[4], u1[4];
        issueH(u0[0], u0[1], u0[2], u0[3], pA[0], pA[1], pA[2], pA[3]);
        #pragma unroll
        for (int c = 0; c < 8; ++c) {
          short8* cur = (c & 1) ? u1 : u0;
          short8* nxt = (c & 1) ? u0 : u1;
          if (c < 7) {
            issueH(nxt[0], nxt[1], nxt[2], nxt[3],
                   pA[0] + (c + 1) * 32, pA[1] + (c + 1) * 32,
                   pA[2] + (c + 1) * 32, pA[3] + (c + 1) * 32);
            waitA4(cur[0], cur[1], cur[2], cur[3]);
          } else {
            waitA0(cur[0], cur[1], cur[2], cur[3]);
          }
          MFMA_CHUNK(cur, wv * 256 + c * 32 + quad * 8);
        }
      } else {
        // layer 0: h-part K=512 (4 chunks/wave, sc1), x-part K=256 (2 chunks/wave, cached f32)
        const int koH = wv * 128 + quad * 8;
        const unsigned short* pH[4];
        const float* pX[4];
        #pragma unroll
        for (int mt = 0; mt < 4; ++mt) {
          pH[mt] = h_self + (16 * mt + m) * HH + koH;
          pX[mt] = x + ((size_t)(16 * mt + m) * TT + t) * DD + wv * 64 + quad * 8;
        }
        short8 u0[4], u1[4];
        f4 xv0[8], xv1[8];
        issueH(u0[0], u0[1], u0[2], u0[3], pH[0], pH[1], pH[2], pH[3]);
        // c0
        issueH(u1[0], u1[1], u1[2], u1[3], pH[0] + 32, pH[1] + 32, pH[2] + 32, pH[3] + 32);
        waitA4(u0[0], u0[1], u0[2], u0[3]);
        MFMA_CHUNK(u0, 256 + koH);
        // c1
        issueH(u0[0], u0[1], u0[2], u0[3], pH[0] + 64, pH[1] + 64, pH[2] + 64, pH[3] + 64);
        waitA4(u1[0], u1[1], u1[2], u1[3]);
        MFMA_CHUNK(u1, 256 + koH + 32);
        // c2
        issueH(u1[0], u1[1], u1[2], u1[3], pH[0] + 96, pH[1] + 96, pH[2] + 96, pH[3] + 96);
        waitA4(u0[0], u0[1], u0[2], u0[3]);
        MFMA_CHUNK(u0, 256 + koH + 64);
        // c3: overlap x issue with last h chunk
        issueX(xv0[0], xv0[1], xv0[2], xv0[3], xv0[4], xv0[5], xv0[6], xv0[7],
               pX[0], pX[1], pX[2], pX[3]);
        waitA8(u1[0], u1[1], u1[2], u1[3]);
        MFMA_CHUNK(u1, 256 + koH + 96);
        // x0
        issueX(xv1[0], xv1[1], xv1[2], xv1[3], xv1[4], xv1[5], xv1[6], xv1[7],
               pX[0] + 32, pX[1] + 32, pX[2] + 32, pX[3] + 32);
        waitX8(xv0[0], xv0[1], xv0[2], xv0[3], xv0[4], xv0[5], xv0[6], xv0[7]);
        {
          short8 a2[4] = {pack8(xv0[0], xv0[1]), pack8(xv0[2], xv0[3]),
                          pack8(xv0[4], xv0[5]), pack8(xv0[6], xv0[7])};
          MFMA_CHUNK(a2, wv * 64 + quad * 8);
        }
        // x1
        waitX0(xv1[0], xv1[1], xv1[2], xv1[3], xv1[4], xv1[5], xv1[6], xv1[7]);
        {
          short8 a2[4] = {pack8(xv1[0], xv1[1]), pack8(xv1[2], xv1[3]),
                          pack8(xv1[4], xv1[5]), pack8(xv1[6], xv1[7])};
          MFMA_CHUNK(a2, wv * 64 + quad * 8 + 32);
        }
      }

      // C/D layout: col = lane&15, row = quad*4 + reg
      #pragma unroll
      for (int mt = 0; mt < 4; ++mt) {
        #pragma unroll
        for (int rg = 0; rg < 4; ++rg) {
          Zp[wv][16 * mt + quad * 4 + rg][col]      = acc[mt][0][rg];
          Zp[wv][16 * mt + quad * 4 + rg][16 + col] = acc[mt][1][rg];
        }
      }
      __syncthreads();

      // ---- phase 2: each thread owns items 2*tid, 2*tid+1 (same b_, j pair) ----
      unsigned short* h_out = hbuf + (l * 2 + wp) * SS;
      {
        const int b_ = tid >> 2;
        const int j  = (tid & 3) * 2;
        float z[4][2];
        #pragma unroll
        for (int g = 0; g < 4; ++g) { z[g][0] = biasl[g * 8 + j]; z[g][1] = biasl[g * 8 + j + 1]; }
        #pragma unroll
        for (int w2 = 0; w2 < 4; ++w2) {
          #pragma unroll
          for (int g = 0; g < 4; ++g) {
            const float2 v = *(const float2*)&Zp[w2][b_][g * 8 + j];
            z[g][0] += v.x; z[g][1] += v.y;
          }
        }
        float hh2[2], cc2[2];
        #pragma unroll
        for (int e = 0; e < 2; ++e) {
          const float gi = sigm(z[0][e]), gf = sigm(z[1][e]);
          const float gz = tanh_(z[2][e]), go = sigm(z[3][e]);
          const float cc = gf * cl[2 * tid + e] + gi * gz;
          cl[2 * tid + e] = cc;
          cc2[e] = cc;
          hh2[e] = go * tanh_(cc);
        }
        const unsigned pk = (unsigned)(unsigned short)f2bf(hh2[0]) |
                            ((unsigned)(unsigned short)f2bf(hh2[1]) << 16);
        stH(h_out + b_ * HH + j0 + j, pk);
        if (t == TT - 1) {
          const int oi = b_ * HH + j0 + j;
          if (l == 0) {
            out[SS + oi] = hh2[0];     out[SS + oi + 1] = hh2[1];
            out[2 * SS + oi] = cc2[0]; out[2 * SS + oi + 1] = cc2[1];
          } else if (l == 1) {
            out[3 * SS + oi] = hh2[0]; out[3 * SS + oi + 1] = hh2[1];
            out[4 * SS + oi] = cc2[0]; out[4 * SS + oi + 1] = cc2[1];
          } else {
            out[oi] = hh2[0];          out[oi + 1] = hh2[1];
            out[5 * SS + oi] = hh2[0]; out[5 * SS + oi + 1] = hh2[1];
            out[6 * SS + oi] = cc2[0]; out[6 * SS + oi + 1] = cc2[1];
          }
        }
      }
      #undef MFMA_CHUNK
    }
    bt += 1; grid_barrier(bt);
  }
}

extern "C" void kernel_launch(void* const* d_in, const int* in_sizes, int n_in,
                              void* d_out, int out_size, void* d_ws, size_t ws_size,
                              hipStream_t stream) {
  const float* x  = (const float*)d_in[0];
  const float* W0 = (const float*)d_in[1];
  const float* U0 = (const float*)d_in[2];
  const float* b0 = (const float*)d_in[3];
  const float* W1 = (const float*)d_in[4];
  const float* U1 = (const float*)d_in[5];
  const float* b1 = (const float*)d_in[6];
  const float* W2 = (const float*)d_in[7];
  const float* U2 = (const float*)d_in[8];
  const float* b2 = (const float*)d_in[9];
  float* out = (float*)d_out;
  unsigned short* hbuf = (unsigned short*)d_ws;

  void* args[] = {(void*)&x,
                  (void*)&W0, (void*)&U0, (void*)&b0,
                  (void*)&W1, (void*)&U1, (void*)&b1,
                  (void*)&W2, (void*)&U2, (void*)&b2,
                  (void*)&out, (void*)&hbuf};
  hipLaunchCooperativeKernel((void*)lstm_persistent, dim3(NBLK), dim3(NTHR),
                             args, 0, stream);
}

// Round 3
// 4352.295 us; speedup vs baseline: 1.9056x; 1.1670x over previous
//
#include <hip/hip_runtime.h>
#include <hip/hip_bf16.h>

// Problem dims
#define BB 64
#define TT 512
#define DD 256
#define HH 512
#define GG 2048            // 4*HH
#define SS (BB*HH)         // 32768 elems per [B,H] slab (64 KB bf16)
#define NBLK 192           // 3 layers x 64 column-slices
#define NTHR 256
#define KPAD 1032          // 1024 + 8 bf16 pad
#define RING 4             // h-ring depth per layer stream

using short8 = __attribute__((ext_vector_type(8))) short;
using f32x4  = __attribute__((ext_vector_type(4))) float;
using f4     = __attribute__((ext_vector_type(4))) float;

// One-time global barrier word (prologue only). Low 32 = arrivals, high 32 = gen.
__device__ unsigned long long g_word = 0;

__device__ __forceinline__ short f2bf(float f) {
  unsigned u = __builtin_bit_cast(unsigned, f);
  u = (u + 0x7fffu + ((u >> 16) & 1u)) >> 16;   // RNE
  return (short)u;
}
__device__ __forceinline__ float sigm(float x)  { return 1.f / (1.f + __expf(-x)); }
__device__ __forceinline__ float tanh_(float x) { return 2.f / (1.f + __expf(-2.f * x)) - 1.f; }

// sc0 sc1 = coherence-point (IC) access: no cache maintenance ever needed.
__device__ __forceinline__ void stH(void* p, unsigned v) {
  asm volatile("global_store_dword %0, %1, off sc0 sc1" :: "v"(p), "v"(v) : "memory");
}
// Poll load of 3 flags (fresh every call).
__device__ __forceinline__ void ld3(int& a, int& b, int& c,
                                    const int* p0, const int* p1, const int* p2) {
  asm volatile("global_load_dword %0, %3, off sc0 sc1\n\t"
               "global_load_dword %1, %4, off sc0 sc1\n\t"
               "global_load_dword %2, %5, off sc0 sc1\n\t"
               "s_waitcnt vmcnt(0)"
               : "=&v"(a), "=&v"(b), "=&v"(c)
               : "v"(p0), "v"(p1), "v"(p2) : "memory");
}

// Deep-pipeline issue/wait macros (literal offsets / counts via stringize).
#define ISSUE_H(A, OFFB, P)                                                      \
  asm volatile("global_load_dwordx4 %0, %4, off offset:" #OFFB " sc0 sc1\n\t"    \
               "global_load_dwordx4 %1, %5, off offset:" #OFFB " sc0 sc1\n\t"    \
               "global_load_dwordx4 %2, %6, off offset:" #OFFB " sc0 sc1\n\t"    \
               "global_load_dwordx4 %3, %7, off offset:" #OFFB " sc0 sc1"        \
               : "=&v"(A[0]), "=&v"(A[1]), "=&v"(A[2]), "=&v"(A[3])              \
               : "v"(P[0]), "v"(P[1]), "v"(P[2]), "v"(P[3]))

#define ISSUE_X(X, O0, O1, P)                                                    \
  asm volatile("global_load_dwordx4 %0, %8, off offset:" #O0 "\n\t"              \
               "global_load_dwordx4 %1, %8, off offset:" #O1 "\n\t"              \
               "global_load_dwordx4 %2, %9, off offset:" #O0 "\n\t"              \
               "global_load_dwordx4 %3, %9, off offset:" #O1 "\n\t"              \
               "global_load_dwordx4 %4, %10, off offset:" #O0 "\n\t"             \
               "global_load_dwordx4 %5, %10, off offset:" #O1 "\n\t"             \
               "global_load_dwordx4 %6, %11, off offset:" #O0 "\n\t"             \
               "global_load_dwordx4 %7, %11, off offset:" #O1                    \
               : "=&v"(X[0]), "=&v"(X[1]), "=&v"(X[2]), "=&v"(X[3]),             \
                 "=&v"(X[4]), "=&v"(X[5]), "=&v"(X[6]), "=&v"(X[7])              \
               : "v"(P[0]), "v"(P[1]), "v"(P[2]), "v"(P[3]))

#define WAIT4(N, A)                                                              \
  asm volatile("s_waitcnt vmcnt(" #N ")"                                         \
               : "+v"(A[0]), "+v"(A[1]), "+v"(A[2]), "+v"(A[3]))
#define WAIT8(N, X)                                                              \
  asm volatile("s_waitcnt vmcnt(" #N ")"                                         \
               : "+v"(X[0]), "+v"(X[1]), "+v"(X[2]), "+v"(X[3]),                 \
                 "+v"(X[4]), "+v"(X[5]), "+v"(X[6]), "+v"(X[7]))

__device__ __forceinline__ short8 pack8(const f4& lo, const f4& hi) {
  return (short8){f2bf(lo[0]), f2bf(lo[1]), f2bf(lo[2]), f2bf(lo[3]),
                  f2bf(hi[0]), f2bf(hi[1]), f2bf(hi[2]), f2bf(hi[3])};
}

__device__ __forceinline__ unsigned short* slab(unsigned short* hb, int l, int t) {
  return hb + ((size_t)(l * RING + (t & (RING - 1)))) * SS;   // t=-1 -> slot 3
}

// One-time fence-free global barrier (prologue handoff only).
__device__ __forceinline__ void grid_barrier(unsigned target) {
  asm volatile("s_waitcnt vmcnt(0)" ::: "memory");
  __syncthreads();
  if (threadIdx.x == 0) {
    unsigned long long old = __hip_atomic_fetch_add(&g_word, 1ull, __ATOMIC_RELAXED,
                                                    __HIP_MEMORY_SCOPE_AGENT);
    if ((unsigned)(old & 0xffffffffull) == NBLK - 1) {
      __hip_atomic_fetch_add(&g_word, (1ull << 32) - (unsigned long long)NBLK,
                             __ATOMIC_RELAXED, __HIP_MEMORY_SCOPE_AGENT);
    } else {
      while ((int)((unsigned)(__hip_atomic_load(&g_word, __ATOMIC_RELAXED,
                                                __HIP_MEMORY_SCOPE_AGENT) >> 32) - target) < 0)
        __builtin_amdgcn_s_sleep(2);
    }
  }
  __syncthreads();
}

extern "C" __global__ __launch_bounds__(NTHR, 1) void lstm_persistent(
    const float* __restrict__ x,
    const float* __restrict__ W0, const float* __restrict__ U0, const float* __restrict__ b0,
    const float* __restrict__ W1, const float* __restrict__ U1, const float* __restrict__ b1,
    const float* __restrict__ W2, const float* __restrict__ U2, const float* __restrict__ b2,
    float* __restrict__ out,
    int* __restrict__ flags,             // ws: 3*64 ints
    unsigned short* __restrict__ hbuf)   // ws+1024: [3][RING][B][H] bf16
{
  __shared__ unsigned short Wl[32][KPAD];   // 66048 B
  __shared__ float Zp[4][BB][34];           // 34816 B
  __shared__ float cl[BB * 8];              // 2048 B
  __shared__ float biasl[32];
  __shared__ unsigned s_gen0;

  const int tid = threadIdx.x;
  const int bid = blockIdx.x;
  const int l = bid % 3;
  const int slice = bid / 3;
  const int j0 = slice * 8;

  if (tid == 0)
    s_gen0 = (unsigned)(__hip_atomic_load(&g_word, __ATOMIC_RELAXED,
                                          __HIP_MEMORY_SCOPE_AGENT) >> 32);

  const float* Wsrc = (l == 0) ? W0 : (l == 1) ? W1 : W2;
  const float* Usrc = (l == 0) ? U0 : (l == 1) ? U1 : U2;
  const float* bsrc = (l == 0) ? b0 : (l == 1) ? b1 : b2;
  const int Kx = (l == 0) ? DD : HH;

  // ---- prologue: weight slice f32->bf16 into LDS ----
  for (int q = 0; q < 4; ++q) {
    const int gcol = q * HH + j0;
    for (int k = tid; k < Kx; k += NTHR) {
      const float* s = Wsrc + (size_t)k * GG + gcol;
      #pragma unroll
      for (int c = 0; c < 8; ++c) Wl[q * 8 + c][k] = (unsigned short)f2bf(s[c]);
    }
    for (int k = tid; k < HH; k += NTHR) {
      const float* s = Usrc + (size_t)k * GG + gcol;
      #pragma unroll
      for (int c = 0; c < 8; ++c) Wl[q * 8 + c][Kx + k] = (unsigned short)f2bf(s[c]);
    }
  }
  if (tid < 32) biasl[tid] = bsrc[(tid >> 3) * HH + j0 + (tid & 7)];
  for (int i = tid; i < BB * 8; i += NTHR) cl[i] = 0.f;

  // zero t=-1 slabs (slot RING-1 of each stream) + flags, all sc1
  for (int l2 = 0; l2 < 3; ++l2) {
    unsigned* zz = (unsigned*)slab(hbuf, l2, -1);
    for (int i = bid * NTHR + tid; i < SS / 2; i += NBLK * NTHR) stH(zz + i, 0u);
  }
  if (bid == 0 && tid < 192) stH(flags + tid, 0u);

  __syncthreads();
  grid_barrier(s_gen0 + 1);   // single global handoff; steady state is dataflow

  const int lane = tid & 63;
  const int wv = tid >> 6;
  const int m = lane & 15;
  const int quad = lane >> 4;
  const int col = lane & 15;

  // poll pointers (wave 0 only; unused deps alias self)
  const int* ps = flags + l * 64 + lane;
  const int* pb = (l > 0) ? flags + (l - 1) * 64 + lane : ps;
  const int* pa = (l < 2) ? flags + (l + 1) * 64 + lane : ps;

  #define MFMA_CHUNK(AV, KKG)                                                     \
    do {                                                                          \
      short8 bf0 = *(const short8*)&Wl[col][(KKG)];                               \
      short8 bf1 = *(const short8*)&Wl[16 + col][(KKG)];                          \
      acc[0][0] = __builtin_amdgcn_mfma_f32_16x16x32_bf16((AV)[0], bf0, acc[0][0], 0, 0, 0); \
      acc[0][1] = __builtin_amdgcn_mfma_f32_16x16x32_bf16((AV)[0], bf1, acc[0][1], 0, 0, 0); \
      acc[1][0] = __builtin_amdgcn_mfma_f32_16x16x32_bf16((AV)[1], bf0, acc[1][0], 0, 0, 0); \
      acc[1][1] = __builtin_amdgcn_mfma_f32_16x16x32_bf16((AV)[1], bf1, acc[1][1], 0, 0, 0); \
      acc[2][0] = __builtin_amdgcn_mfma_f32_16x16x32_bf16((AV)[2], bf0, acc[2][0], 0, 0, 0); \
      acc[2][1] = __builtin_amdgcn_mfma_f32_16x16x32_bf16((AV)[2], bf1, acc[2][1], 0, 0, 0); \
      acc[3][0] = __builtin_amdgcn_mfma_f32_16x16x32_bf16((AV)[3], bf0, acc[3][0], 0, 0, 0); \
      acc[3][1] = __builtin_amdgcn_mfma_f32_16x16x32_bf16((AV)[3], bf1, acc[3][1], 0, 0, 0); \
    } while (0)

  for (int t = 0; t < TT; ++t) {
    // ---- dataflow wait: self peers done t-1; below published t; above drained slot ----
    if (tid < 64) {
      for (;;) {
        int fs, fb, fa;
        ld3(fs, fb, fa, ps, pb, pa);
        bool ok = (fs >= t);
        if (l > 0) ok = ok && (fb >= t + 1);
        if (l < 2) ok = ok && (fa >= t - (RING - 1));
        if (__all(ok)) break;
        __builtin_amdgcn_s_sleep(1);
      }
    }
    __syncthreads();

    const unsigned short* h_self = slab(hbuf, l, t - 1);

    f32x4 acc[4][2];
    #pragma unroll
    for (int mt = 0; mt < 4; ++mt) {
      acc[mt][0] = (f32x4){0.f, 0.f, 0.f, 0.f};
      acc[mt][1] = (f32x4){0.f, 0.f, 0.f, 0.f};
    }

    if (l > 0) {
      // K=1024: waves 0,1 -> h_below[0,512); waves 2,3 -> h_self. 8 chunks, all in flight.
      const unsigned short* h_below = slab(hbuf, l - 1, t);
      const unsigned short* src = (wv < 2) ? h_below : h_self;
      const int ko0 = (wv & 1) * 256 + quad * 8;
      const unsigned short* pA[4];
      #pragma unroll
      for (int mt = 0; mt < 4; ++mt) pA[mt] = src + (16 * mt + m) * HH + ko0;

      short8 u0[4], u1[4], u2[4], u3[4], u4[4], u5[4], u6[4], u7[4];
      ISSUE_H(u0,   0, pA); ISSUE_H(u1,  64, pA); ISSUE_H(u2, 128, pA); ISSUE_H(u3, 192, pA);
      ISSUE_H(u4, 256, pA); ISSUE_H(u5, 320, pA); ISSUE_H(u6, 384, pA); ISSUE_H(u7, 448, pA);
      const int kb = wv * 256 + quad * 8;
      WAIT4(28, u0); MFMA_CHUNK(u0, kb);
      WAIT4(24, u1); MFMA_CHUNK(u1, kb + 32);
      WAIT4(20, u2); MFMA_CHUNK(u2, kb + 64);
      WAIT4(16, u3); MFMA_CHUNK(u3, kb + 96);
      WAIT4(12, u4); MFMA_CHUNK(u4, kb + 128);
      WAIT4( 8, u5); MFMA_CHUNK(u5, kb + 160);
      WAIT4( 4, u6); MFMA_CHUNK(u6, kb + 192);
      WAIT4( 0, u7); MFMA_CHUNK(u7, kb + 224);
    } else {
      // layer 0: h K=512 (4 chunks/wave, sc1) + x K=256 (2 chunks/wave, cached)
      const int koH = wv * 128 + quad * 8;
      const unsigned short* pH[4];
      const float* pX[4];
      #pragma unroll
      for (int mt = 0; mt < 4; ++mt) {
        pH[mt] = h_self + (16 * mt + m) * HH + koH;
        pX[mt] = x + ((size_t)(16 * mt + m) * TT + t) * DD + wv * 64 + quad * 8;
      }
      short8 u0[4], u1[4], u2[4], u3[4];
      f4 xv0[8], xv1[8];
      ISSUE_H(u0, 0, pH); ISSUE_H(u1, 64, pH); ISSUE_H(u2, 128, pH); ISSUE_H(u3, 192, pH);
      ISSUE_X(xv0, 0, 16, pX);
      ISSUE_X(xv1, 128, 144, pX);
      const int kb = 256 + koH;
      WAIT4(28, u0); MFMA_CHUNK(u0, kb);
      WAIT4(24, u1); MFMA_CHUNK(u1, kb + 32);
      WAIT4(20, u2); MFMA_CHUNK(u2, kb + 64);
      WAIT4(16, u3); MFMA_CHUNK(u3, kb + 96);
      WAIT8(8, xv0);
      {
        short8 a2[4] = {pack8(xv0[0], xv0[1]), pack8(xv0[2], xv0[3]),
                        pack8(xv0[4], xv0[5]), pack8(xv0[6], xv0[7])};
        MFMA_CHUNK(a2, wv * 64 + quad * 8);
      }
      WAIT8(0, xv1);
      {
        short8 a2[4] = {pack8(xv1[0], xv1[1]), pack8(xv1[2], xv1[3]),
                        pack8(xv1[4], xv1[5]), pack8(xv1[6], xv1[7])};
        MFMA_CHUNK(a2, wv * 64 + quad * 8 + 32);
      }
    }

    // C/D layout: col = lane&15, row = quad*4 + reg
    #pragma unroll
    for (int mt = 0; mt < 4; ++mt) {
      #pragma unroll
      for (int rg = 0; rg < 4; ++rg) {
        Zp[wv][16 * mt + quad * 4 + rg][col]      = acc[mt][0][rg];
        Zp[wv][16 * mt + quad * 4 + rg][16 + col] = acc[mt][1][rg];
      }
    }
    __syncthreads();

    // ---- phase 2: gates + state; each thread owns (b_, j..j+1) ----
    unsigned short* h_out = slab(hbuf, l, t);
    {
      const int b_ = tid >> 2;
      const int j  = (tid & 3) * 2;
      float z[4][2];
      #pragma unroll
      for (int g = 0; g < 4; ++g) { z[g][0] = biasl[g * 8 + j]; z[g][1] = biasl[g * 8 + j + 1]; }
      #pragma unroll
      for (int w2 = 0; w2 < 4; ++w2) {
        #pragma unroll
        for (int g = 0; g < 4; ++g) {
          const float2 v = *(const float2*)&Zp[w2][b_][g * 8 + j];
          z[g][0] += v.x; z[g][1] += v.y;
        }
      }
      float hh2[2], cc2[2];
      #pragma unroll
      for (int e = 0; e < 2; ++e) {
        const float gi = sigm(z[0][e]), gf = sigm(z[1][e]);
        const float gz = tanh_(z[2][e]), go = sigm(z[3][e]);
        const float cc = gf * cl[2 * tid + e] + gi * gz;
        cl[2 * tid + e] = cc;
        cc2[e] = cc;
        hh2[e] = go * tanh_(cc);
      }
      const unsigned pk = (unsigned)(unsigned short)f2bf(hh2[0]) |
                          ((unsigned)(unsigned short)f2bf(hh2[1]) << 16);
      stH(h_out + b_ * HH + j0 + j, pk);
      if (t == TT - 1) {
        const int oi = b_ * HH + j0 + j;
        if (l == 0) {
          out[SS + oi] = hh2[0];     out[SS + oi + 1] = hh2[1];
          out[2 * SS + oi] = cc2[0]; out[2 * SS + oi + 1] = cc2[1];
        } else if (l == 1) {
          out[3 * SS + oi] = hh2[0]; out[3 * SS + oi + 1] = hh2[1];
          out[4 * SS + oi] = cc2[0]; out[4 * SS + oi + 1] = cc2[1];
        } else {
          out[oi] = hh2[0];          out[oi + 1] = hh2[1];
          out[5 * SS + oi] = hh2[0]; out[5 * SS + oi + 1] = hh2[1];
          out[6 * SS + oi] = cc2[0]; out[6 * SS + oi + 1] = cc2[1];
        }
      }
    }

    // ---- publish: drain h stores, then flag ----
    asm volatile("s_waitcnt vmcnt(0)" ::: "memory");
    __syncthreads();
    if (tid == 0) stH(flags + l * 64 + slice, (unsigned)(t + 1));
  }
  #undef MFMA_CHUNK
}

extern "C" void kernel_launch(void* const* d_in, const int* in_sizes, int n_in,
                              void* d_out, int out_size, void* d_ws, size_t ws_size,
                              hipStream_t stream) {
  const float* x  = (const float*)d_in[0];
  const float* W0 = (const float*)d_in[1];
  const float* U0 = (const float*)d_in[2];
  const float* b0 = (const float*)d_in[3];
  const float* W1 = (const float*)d_in[4];
  const float* U1 = (const float*)d_in[5];
  const float* b1 = (const float*)d_in[6];
  const float* W2 = (const float*)d_in[7];
  const float* U2 = (const float*)d_in[8];
  const float* b2 = (const float*)d_in[9];
  float* out = (float*)d_out;
  int* flags = (int*)d_ws;
  unsigned short* hbuf = (unsigned short*)((char*)d_ws + 1024);  // + 3*RING*64KB

  void* args[] = {(void*)&x,
                  (void*)&W0, (void*)&U0, (void*)&b0,
                  (void*)&W1, (void*)&U1, (void*)&b1,
                  (void*)&W2, (void*)&U2, (void*)&b2,
                  (void*)&out, (void*)&flags, (void*)&hbuf};
  hipLaunchCooperativeKernel((void*)lstm_persistent, dim3(NBLK), dim3(NTHR),
                             args, 0, stream);
}

// Round 6
// 4159.607 us; speedup vs baseline: 1.9939x; 1.0463x over previous
//
#include <hip/hip_runtime.h>
#include <hip/hip_bf16.h>

// Problem dims
#define BB 64
#define TT 512
#define DD 256
#define HH 512
#define GG 2048            // 4*HH
#define SS (BB*HH)         // 32768 elems per [B,H] slab (64 KB bf16)
#define NBLK 192           // 3 layers x 64 column-slices
#define NTHR 256
#define KPAD 1032          // 1024 + 8 bf16 pad

using short8 = __attribute__((ext_vector_type(8))) short;
using f32x4  = __attribute__((ext_vector_type(4))) float;
using f4     = __attribute__((ext_vector_type(4))) float;

// One-time global barrier word (prologue only). Low 32 = arrivals, high 32 = gen.
__device__ unsigned long long g_word = 0;

__device__ __forceinline__ short f2bf(float f) {
  unsigned u = __builtin_bit_cast(unsigned, f);
  u = (u + 0x7fffu + ((u >> 16) & 1u)) >> 16;   // RNE
  return (short)u;
}
__device__ __forceinline__ float sigm(float x)  { return 1.f / (1.f + __expf(-x)); }
__device__ __forceinline__ float tanh_(float x) { return 2.f / (1.f + __expf(-2.f * x)) - 1.f; }

// sc0 sc1 = coherence-point (IC) access: used for h STORES + flag protocol.
__device__ __forceinline__ void stH(void* p, unsigned v) {
  asm volatile("global_store_dword %0, %1, off sc0 sc1" :: "v"(p), "v"(v) : "memory");
}
// Poll load of 3 flags (fresh every call) -- v3-proven.
__device__ __forceinline__ void ld3(int& a, int& b, int& c,
                                    const int* p0, const int* p1, const int* p2) {
  asm volatile("global_load_dword %0, %3, off sc0 sc1\n\t"
               "global_load_dword %1, %4, off sc0 sc1\n\t"
               "global_load_dword %2, %5, off sc0 sc1\n\t"
               "s_waitcnt vmcnt(0)"
               : "=&v"(a), "=&v"(b), "=&v"(c)
               : "v"(p0), "v"(p1), "v"(p2) : "memory");
}

// sc1 (IC-direct) A loads -- fallback path (small ring, addresses reused).
#define ISSUE_H(A, OFFB, P)                                                      \
  asm volatile("global_load_dwordx4 %0, %4, off offset:" #OFFB " sc0 sc1\n\t"    \
               "global_load_dwordx4 %1, %5, off offset:" #OFFB " sc0 sc1\n\t"    \
               "global_load_dwordx4 %2, %6, off offset:" #OFFB " sc0 sc1\n\t"    \
               "global_load_dwordx4 %3, %7, off offset:" #OFFB " sc0 sc1"        \
               : "=&v"(A[0]), "=&v"(A[1]), "=&v"(A[2]), "=&v"(A[3])              \
               : "v"(P[0]), "v"(P[1]), "v"(P[2]), "v"(P[3]))

// Normally-cached A loads -- big-ring path: every slab address written exactly
// once per call => L2 can never hold a stale copy; per-XCD L2 dedups the 24
// same-XCD duplicate readers of each slab.
#define ISSUE_HC(A, OFFB, P)                                                     \
  asm volatile("global_load_dwordx4 %0, %4, off offset:" #OFFB "\n\t"            \
               "global_load_dwordx4 %1, %5, off offset:" #OFFB "\n\t"            \
               "global_load_dwordx4 %2, %6, off offset:" #OFFB "\n\t"            \
               "global_load_dwordx4 %3, %7, off offset:" #OFFB                   \
               : "=&v"(A[0]), "=&v"(A[1]), "=&v"(A[2]), "=&v"(A[3])              \
               : "v"(P[0]), "v"(P[1]), "v"(P[2]), "v"(P[3]))

#define ISSUE_X(X, O0, O1, P)                                                    \
  asm volatile("global_load_dwordx4 %0, %8, off offset:" #O0 "\n\t"              \
               "global_load_dwordx4 %1, %8, off offset:" #O1 "\n\t"              \
               "global_load_dwordx4 %2, %9, off offset:" #O0 "\n\t"              \
               "global_load_dwordx4 %3, %9, off offset:" #O1 "\n\t"              \
               "global_load_dwordx4 %4, %10, off offset:" #O0 "\n\t"             \
               "global_load_dwordx4 %5, %10, off offset:" #O1 "\n\t"             \
               "global_load_dwordx4 %6, %11, off offset:" #O0 "\n\t"             \
               "global_load_dwordx4 %7, %11, off offset:" #O1                    \
               : "=&v"(X[0]), "=&v"(X[1]), "=&v"(X[2]), "=&v"(X[3]),             \
                 "=&v"(X[4]), "=&v"(X[5]), "=&v"(X[6]), "=&v"(X[7])              \
               : "v"(P[0]), "v"(P[1]), "v"(P[2]), "v"(P[3]))

#define WAIT4(N, A)                                                              \
  asm volatile("s_waitcnt vmcnt(" #N ")"                                         \
               : "+v"(A[0]), "+v"(A[1]), "+v"(A[2]), "+v"(A[3]))
#define WAIT8(N, X)                                                              \
  asm volatile("s_waitcnt vmcnt(" #N ")"                                         \
               : "+v"(X[0]), "+v"(X[1]), "+v"(X[2]), "+v"(X[3]),                 \
                 "+v"(X[4]), "+v"(X[5]), "+v"(X[6]), "+v"(X[7]))

__device__ __forceinline__ short8 pack8(const f4& lo, const f4& hi) {
  return (short8){f2bf(lo[0]), f2bf(lo[1]), f2bf(lo[2]), f2bf(lo[3]),
                  f2bf(hi[0]), f2bf(hi[1]), f2bf(hi[2]), f2bf(hi[3])};
}

// One-time fence-free global barrier (prologue handoff only) -- v3-proven.
__device__ __forceinline__ void grid_barrier(unsigned target) {
  asm volatile("s_waitcnt vmcnt(0)" ::: "memory");
  __syncthreads();
  if (threadIdx.x == 0) {
    unsigned long long old = __hip_atomic_fetch_add(&g_word, 1ull, __ATOMIC_RELAXED,
                                                    __HIP_MEMORY_SCOPE_AGENT);
    if ((unsigned)(old & 0xffffffffull) == NBLK - 1) {
      __hip_atomic_fetch_add(&g_word, (1ull << 32) - (unsigned long long)NBLK,
                             __ATOMIC_RELAXED, __HIP_MEMORY_SCOPE_AGENT);
    } else {
      while ((int)((unsigned)(__hip_atomic_load(&g_word, __ATOMIC_RELAXED,
                                                __HIP_MEMORY_SCOPE_AGENT) >> 32) - target) < 0)
        __builtin_amdgcn_s_sleep(2);
    }
  }
  __syncthreads();
}

extern "C" __global__ __launch_bounds__(NTHR, 1) void lstm_persistent(
    const float* __restrict__ x,
    const float* __restrict__ W0, const float* __restrict__ U0, const float* __restrict__ b0,
    const float* __restrict__ W1, const float* __restrict__ U1, const float* __restrict__ b1,
    const float* __restrict__ W2, const float* __restrict__ U2, const float* __restrict__ b2,
    float* __restrict__ out,
    int* __restrict__ flags,             // ws: 3*64 ints
    unsigned short* __restrict__ hbuf,   // ws+1024: [3][ring][B][H] bf16
    int big, int rmask)                  // big: ring covers all T -> cached A loads
{
  __shared__ unsigned short Wl[32][KPAD];   // 66048 B
  __shared__ float Zp[4][BB][34];           // 34816 B
  __shared__ float cl[BB * 8];              // 2048 B
  __shared__ float biasl[32];
  __shared__ unsigned s_gen0;

  const int tid = threadIdx.x;
  const int bid = blockIdx.x;
  const int l = bid % 3;
  const int slice = bid / 3;
  const int j0 = slice * 8;
  const int ringsz = rmask + 1;

  if (tid == 0)
    s_gen0 = (unsigned)(__hip_atomic_load(&g_word, __ATOMIC_RELAXED,
                                          __HIP_MEMORY_SCOPE_AGENT) >> 32);

  const float* Wsrc = (l == 0) ? W0 : (l == 1) ? W1 : W2;
  const float* Usrc = (l == 0) ? U0 : (l == 1) ? U1 : U2;
  const float* bsrc = (l == 0) ? b0 : (l == 1) ? b1 : b2;
  const int Kx = (l == 0) ? DD : HH;

  // slab address for (layer, t); t = -1 maps to the last ring slot.
  #define SLAB(LL, T_) (hbuf + (size_t)((LL) * ringsz + ((T_) & rmask)) * SS)

  // ---- prologue: weight slice f32->bf16 into LDS ----
  for (int q = 0; q < 4; ++q) {
    const int gcol = q * HH + j0;
    for (int k = tid; k < Kx; k += NTHR) {
      const float* s = Wsrc + (size_t)k * GG + gcol;
      #pragma unroll
      for (int c = 0; c < 8; ++c) Wl[q * 8 + c][k] = (unsigned short)f2bf(s[c]);
    }
    for (int k = tid; k < HH; k += NTHR) {
      const float* s = Usrc + (size_t)k * GG + gcol;
      #pragma unroll
      for (int c = 0; c < 8; ++c) Wl[q * 8 + c][Kx + k] = (unsigned short)f2bf(s[c]);
    }
  }
  if (tid < 32) biasl[tid] = bsrc[(tid >> 3) * HH + j0 + (tid & 7)];
  for (int i = tid; i < BB * 8; i += NTHR) cl[i] = 0.f;

  // zero t=-1 slabs + flags, sc1 (v3-proven protocol)
  for (int l2 = 0; l2 < 3; ++l2) {
    unsigned* zz = (unsigned*)SLAB(l2, -1);
    for (int i = bid * NTHR + tid; i < SS / 2; i += NBLK * NTHR) stH(zz + i, 0u);
  }
  if (bid == 0 && tid < 192) stH(flags + tid, 0u);

  __syncthreads();
  grid_barrier(s_gen0 + 1);   // single global handoff; steady state is dataflow

  const int lane = tid & 63;
  const int wv = tid >> 6;
  const int m = lane & 15;
  const int quad = lane >> 4;
  const int col = lane & 15;

  // poll pointers (wave 0 only; unused deps alias self) -- v3 exact
  const int* ps = flags + l * 64 + lane;
  const int* pb = (l > 0) ? flags + (l - 1) * 64 + lane : ps;
  const int* pa = (l < 2) ? flags + (l + 1) * 64 + lane : ps;

  #define MFMA_CHUNK(AV, KKG)                                                     \
    do {                                                                          \
      short8 bf0 = *(const short8*)&Wl[col][(KKG)];                               \
      short8 bf1 = *(const short8*)&Wl[16 + col][(KKG)];                          \
      acc[0][0] = __builtin_amdgcn_mfma_f32_16x16x32_bf16((AV)[0], bf0, acc[0][0], 0, 0, 0); \
      acc[0][1] = __builtin_amdgcn_mfma_f32_16x16x32_bf16((AV)[0], bf1, acc[0][1], 0, 0, 0); \
      acc[1][0] = __builtin_amdgcn_mfma_f32_16x16x32_bf16((AV)[1], bf0, acc[1][0], 0, 0, 0); \
      acc[1][1] = __builtin_amdgcn_mfma_f32_16x16x32_bf16((AV)[1], bf1, acc[1][1], 0, 0, 0); \
      acc[2][0] = __builtin_amdgcn_mfma_f32_16x16x32_bf16((AV)[2], bf0, acc[2][0], 0, 0, 0); \
      acc[2][1] = __builtin_amdgcn_mfma_f32_16x16x32_bf16((AV)[2], bf1, acc[2][1], 0, 0, 0); \
      acc[3][0] = __builtin_amdgcn_mfma_f32_16x16x32_bf16((AV)[3], bf0, acc[3][0], 0, 0, 0); \
      acc[3][1] = __builtin_amdgcn_mfma_f32_16x16x32_bf16((AV)[3], bf1, acc[3][1], 0, 0, 0); \
    } while (0)

  for (int t = 0; t < TT; ++t) {
    // ---- dataflow wait: v3 exact (wave-0 ld3 poll of per-slice flags) ----
    if (tid < 64) {
      for (;;) {
        int fs, fb, fa;
        ld3(fs, fb, fa, ps, pb, pa);
        bool ok = (fs >= t);
        if (l > 0) ok = ok && (fb >= t + 1);
        if (l < 2) ok = ok && (fa >= t - rmask);
        if (__all(ok)) break;
        __builtin_amdgcn_s_sleep(1);
      }
    }
    __syncthreads();

    const unsigned short* h_self = SLAB(l, t - 1);

    f32x4 acc[4][2];
    #pragma unroll
    for (int mt = 0; mt < 4; ++mt) {
      acc[mt][0] = (f32x4){0.f, 0.f, 0.f, 0.f};
      acc[mt][1] = (f32x4){0.f, 0.f, 0.f, 0.f};
    }

    if (l > 0) {
      // K=1024: waves 0,1 -> h_below[0,512); waves 2,3 -> h_self. 8 chunks in flight.
      const unsigned short* h_below = SLAB(l - 1, t);
      const unsigned short* src = (wv < 2) ? h_below : h_self;
      const int ko0 = (wv & 1) * 256 + quad * 8;
      const unsigned short* pA[4];
      #pragma unroll
      for (int mt = 0; mt < 4; ++mt) pA[mt] = src + (16 * mt + m) * HH + ko0;

      short8 u0[4], u1[4], u2[4], u3[4], u4[4], u5[4], u6[4], u7[4];
      if (big) {
        ISSUE_HC(u0,   0, pA); ISSUE_HC(u1,  64, pA); ISSUE_HC(u2, 128, pA); ISSUE_HC(u3, 192, pA);
        ISSUE_HC(u4, 256, pA); ISSUE_HC(u5, 320, pA); ISSUE_HC(u6, 384, pA); ISSUE_HC(u7, 448, pA);
      } else {
        ISSUE_H(u0,   0, pA); ISSUE_H(u1,  64, pA); ISSUE_H(u2, 128, pA); ISSUE_H(u3, 192, pA);
        ISSUE_H(u4, 256, pA); ISSUE_H(u5, 320, pA); ISSUE_H(u6, 384, pA); ISSUE_H(u7, 448, pA);
      }
      const int kb = wv * 256 + quad * 8;
      WAIT4(28, u0); MFMA_CHUNK(u0, kb);
      WAIT4(24, u1); MFMA_CHUNK(u1, kb + 32);
      WAIT4(20, u2); MFMA_CHUNK(u2, kb + 64);
      WAIT4(16, u3); MFMA_CHUNK(u3, kb + 96);
      WAIT4(12, u4); MFMA_CHUNK(u4, kb + 128);
      WAIT4( 8, u5); MFMA_CHUNK(u5, kb + 160);
      WAIT4( 4, u6); MFMA_CHUNK(u6, kb + 192);
      WAIT4( 0, u7); MFMA_CHUNK(u7, kb + 224);
    } else {
      // layer 0: h K=512 (4 chunks/wave) + x K=256 (2 chunks/wave, cached) -- v3 order.
      const int koH = wv * 128 + quad * 8;
      const unsigned short* pH[4];
      const float* pX[4];
      #pragma unroll
      for (int mt = 0; mt < 4; ++mt) {
        pH[mt] = h_self + (16 * mt + m) * HH + koH;
        pX[mt] = x + ((size_t)(16 * mt + m) * TT + t) * DD + wv * 64 + quad * 8;
      }
      short8 u0[4], u1[4], u2[4], u3[4];
      f4 xv0[8], xv1[8];
      if (big) {
        ISSUE_HC(u0, 0, pH); ISSUE_HC(u1, 64, pH); ISSUE_HC(u2, 128, pH); ISSUE_HC(u3, 192, pH);
      } else {
        ISSUE_H(u0, 0, pH); ISSUE_H(u1, 64, pH); ISSUE_H(u2, 128, pH); ISSUE_H(u3, 192, pH);
      }
      ISSUE_X(xv0, 0, 16, pX);
      ISSUE_X(xv1, 128, 144, pX);
      const int kb = 256 + koH;
      WAIT4(28, u0); MFMA_CHUNK(u0, kb);
      WAIT4(24, u1); MFMA_CHUNK(u1, kb + 32);
      WAIT4(20, u2); MFMA_CHUNK(u2, kb + 64);
      WAIT4(16, u3); MFMA_CHUNK(u3, kb + 96);
      WAIT8(8, xv0);
      {
        short8 a2[4] = {pack8(xv0[0], xv0[1]), pack8(xv0[2], xv0[3]),
                        pack8(xv0[4], xv0[5]), pack8(xv0[6], xv0[7])};
        MFMA_CHUNK(a2, wv * 64 + quad * 8);
      }
      WAIT8(0, xv1);
      {
        short8 a2[4] = {pack8(xv1[0], xv1[1]), pack8(xv1[2], xv1[3]),
                        pack8(xv1[4], xv1[5]), pack8(xv1[6], xv1[7])};
        MFMA_CHUNK(a2, wv * 64 + quad * 8 + 32);
      }
    }

    // C/D layout: col = lane&15, row = quad*4 + reg
    #pragma unroll
    for (int mt = 0; mt < 4; ++mt) {
      #pragma unroll
      for (int rg = 0; rg < 4; ++rg) {
        Zp[wv][16 * mt + quad * 4 + rg][col]      = acc[mt][0][rg];
        Zp[wv][16 * mt + quad * 4 + rg][16 + col] = acc[mt][1][rg];
      }
    }
    __syncthreads();

    // ---- phase 2: gates + state; each thread owns (b_, j..j+1) ----
    unsigned short* h_out = SLAB(l, t);
    {
      const int b_ = tid >> 2;
      const int j  = (tid & 3) * 2;
      float z[4][2];
      #pragma unroll
      for (int g = 0; g < 4; ++g) { z[g][0] = biasl[g * 8 + j]; z[g][1] = biasl[g * 8 + j + 1]; }
      #pragma unroll
      for (int w2 = 0; w2 < 4; ++w2) {
        #pragma unroll
        for (int g = 0; g < 4; ++g) {
          const float2 v = *(const float2*)&Zp[w2][b_][g * 8 + j];
          z[g][0] += v.x; z[g][1] += v.y;
        }
      }
      float hh2[2], cc2[2];
      #pragma unroll
      for (int e = 0; e < 2; ++e) {
        const float gi = sigm(z[0][e]), gf = sigm(z[1][e]);
        const float gz = tanh_(z[2][e]), go = sigm(z[3][e]);
        const float cc = gf * cl[2 * tid + e] + gi * gz;
        cl[2 * tid + e] = cc;
        cc2[e] = cc;
        hh2[e] = go * tanh_(cc);
      }
      const unsigned pk = (unsigned)(unsigned short)f2bf(hh2[0]) |
                          ((unsigned)(unsigned short)f2bf(hh2[1]) << 16);
      stH(h_out + b_ * HH + j0 + j, pk);
      if (t == TT - 1) {
        const int oi = b_ * HH + j0 + j;
        if (l == 0) {
          out[SS + oi] = hh2[0];     out[SS + oi + 1] = hh2[1];
          out[2 * SS + oi] = cc2[0]; out[2 * SS + oi + 1] = cc2[1];
        } else if (l == 1) {
          out[3 * SS + oi] = hh2[0]; out[3 * SS + oi + 1] = hh2[1];
          out[4 * SS + oi] = cc2[0]; out[4 * SS + oi + 1] = cc2[1];
        } else {
          out[oi] = hh2[0];          out[oi + 1] = hh2[1];
          out[5 * SS + oi] = hh2[0]; out[5 * SS + oi + 1] = hh2[1];
          out[6 * SS + oi] = cc2[0]; out[6 * SS + oi + 1] = cc2[1];
        }
      }
    }

    // ---- publish: drain h stores to IC, then flag (v3 exact) ----
    asm volatile("s_waitcnt vmcnt(0)" ::: "memory");
    __syncthreads();
    if (tid == 0) stH(flags + l * 64 + slice, (unsigned)(t + 1));
  }
  #undef MFMA_CHUNK
  #undef SLAB
}

extern "C" void kernel_launch(void* const* d_in, const int* in_sizes, int n_in,
                              void* d_out, int out_size, void* d_ws, size_t ws_size,
                              hipStream_t stream) {
  const float* x  = (const float*)d_in[0];
  const float* W0 = (const float*)d_in[1];
  const float* U0 = (const float*)d_in[2];
  const float* b0 = (const float*)d_in[3];
  const float* W1 = (const float*)d_in[4];
  const float* U1 = (const float*)d_in[5];
  const float* b1 = (const float*)d_in[6];
  const float* W2 = (const float*)d_in[7];
  const float* U2 = (const float*)d_in[8];
  const float* b2 = (const float*)d_in[9];
  float* out = (float*)d_out;
  int* flags = (int*)d_ws;
  unsigned short* hbuf = (unsigned short*)((char*)d_ws + 1024);

  // Big ring (full T: no h address rewritten within a call -> cached A loads
  // are staleness-free) if the workspace fits it; else v3 fallback (RING=4, sc1).
  const size_t big_bytes = 1024 + (size_t)3 * TT * SS * 2;   // ~96 MB
  int big   = (ws_size >= big_bytes) ? 1 : 0;
  int rmask = big ? (TT - 1) : 3;

  void* args[] = {(void*)&x,
                  (void*)&W0, (void*)&U0, (void*)&b0,
                  (void*)&W1, (void*)&U1, (void*)&b1,
                  (void*)&W2, (void*)&U2, (void*)&b2,
                  (void*)&out, (void*)&flags, (void*)&hbuf,
                  (void*)&big, (void*)&rmask};
  hipLaunchCooperativeKernel((void*)lstm_persistent, dim3(NBLK), dim3(NTHR),
                             args, 0, stream);
}